// Round 5
// baseline (2559.017 us; speedup 1.0000x reference)
//
#include <hip/hip_runtime.h>
#include <math.h>

// ROUND 5: LOCALIZATION BUILD — pure f32 vector-ALU pipeline, no MFMA, no f16.
//   info = x x^T is symmetric, never materialized:
//     emb = x (x^T e1W^T) + b1 ;  WT = x (x^T v) ;  z = q WT^T
//   attn = tanh(z/sqrt(E)); h = attn v; out = relu(hcat e2W^T + b2)
//   k path is dead code in the reference -> skipped.
// If this passes, algebra+plumbing are proven and MFMA gets re-added stagewise.

typedef float f32x4 __attribute__((ext_vector_type(4)));

static constexpr int BB = 8, NN = 2048, DD = 128, EE = 128, HH = 4;

struct ZMap { int div; int mod; long long str; };

enum { E_STORE = 0, E_BCOL = 1, E_BROW = 2, E_TANH = 3, E_RELU = 4, E_ATOM = 5 };

// x [BCH,N,D] f32 -> xT [BCH,D,N] f32 (32x32 LDS tile transpose)
__global__ void transp_x(const float* __restrict__ x, float* __restrict__ xT) {
  __shared__ float t[32][33];
  const int b = blockIdx.z, n0 = blockIdx.y * 32, d0 = blockIdx.x * 32;
  const int tr = threadIdx.x >> 3, tc = (threadIdx.x & 7) * 4;
  f32x4 v = *(const f32x4*)(x + ((long long)b * NN + n0 + tr) * DD + d0 + tc);
  t[tr][tc + 0] = v[0]; t[tr][tc + 1] = v[1];
  t[tr][tc + 2] = v[2]; t[tr][tc + 3] = v[3];
  __syncthreads();
  f32x4 o = { t[tc + 0][tr], t[tc + 1][tr], t[tc + 2][tr], t[tc + 3][tr] };
  *(f32x4*)(xT + ((long long)b * DD + d0 + tr) * NN + n0 + tc) = o;
}

// C[M,N'] = A[M,K] (row-major, lda) * Bt[N',K]^T (row-major, ldb), pure f32.
// 128x128 tile, BK=16, 256 threads (16x16), 8x8 microtile per thread.
// LDS stored k-major [16][132]: A-frag reads broadcast, B-frag f32x4 reads.
template <int EPI>
__launch_bounds__(256)
__global__ void gemm32(const float* __restrict__ A, ZMap za,
                       const float* __restrict__ Bt, ZMap zb,
                       float* __restrict__ C, ZMap zc, ZMap zc2,
                       const float* __restrict__ bias, ZMap ze,
                       int K, int ksplit, int lda, int ldb, int ldc, float scale) {
  constexpr int LD = 132;
  __shared__ float As[16 * LD];
  __shared__ float Bs[16 * LD];
  const int tid = threadIdx.x;
  const int z = blockIdx.z;
  const int kc = z % ksplit, kn = K / ksplit, k0 = kc * kn;
  const float* Ab = A + (long long)((z / za.div) % za.mod) * za.str +
                    (long long)blockIdx.y * 128 * lda;
  const float* Bb = Bt + (long long)((z / zb.div) % zb.mod) * zb.str +
                    (long long)blockIdx.x * 128 * ldb;
  const int ty = tid >> 4, tx = tid & 15;

  float acc[8][8] = {};
  for (int kk = k0; kk < k0 + kn; kk += 16) {
#pragma unroll
    for (int i = 0; i < 2; ++i) {
      int g = i * 256 + tid, r = g >> 2, c = (g & 3) * 4;
      f32x4 va = *(const f32x4*)(Ab + (long long)r * lda + kk + c);
      f32x4 vb = *(const f32x4*)(Bb + (long long)r * ldb + kk + c);
#pragma unroll
      for (int j = 0; j < 4; ++j) {      // k-major store; write conflicts 2-way (free)
        As[(c + j) * LD + r] = va[j];
        Bs[(c + j) * LD + r] = vb[j];
      }
    }
    __syncthreads();
#pragma unroll
    for (int k = 0; k < 16; ++k) {
      f32x4 a0 = *(const f32x4*)(As + k * LD + ty * 8);
      f32x4 a1 = *(const f32x4*)(As + k * LD + ty * 8 + 4);
      f32x4 b0 = *(const f32x4*)(Bs + k * LD + tx * 8);
      f32x4 b1 = *(const f32x4*)(Bs + k * LD + tx * 8 + 4);
      float ar[8] = { a0[0], a0[1], a0[2], a0[3], a1[0], a1[1], a1[2], a1[3] };
      float br[8] = { b0[0], b0[1], b0[2], b0[3], b1[0], b1[1], b1[2], b1[3] };
#pragma unroll
      for (int i = 0; i < 8; ++i)
#pragma unroll
        for (int j = 0; j < 8; ++j)
          acc[i][j] += ar[i] * br[j];    // contracts to v_fmac_f32
    }
    __syncthreads();
  }

  long long coff = (long long)((z / zc.div) % zc.mod) * zc.str +
                   (long long)((z / zc2.div) % zc2.mod) * zc2.str;
  const float* bp = bias ? bias + (long long)((z / ze.div) % ze.mod) * ze.str : nullptr;
#pragma unroll
  for (int i = 0; i < 8; ++i) {
    int row = (int)blockIdx.y * 128 + ty * 8 + i;
#pragma unroll
    for (int j = 0; j < 8; ++j) {
      int col = (int)blockIdx.x * 128 + tx * 8 + j;
      float v = acc[i][j];
      long long off = coff + (long long)row * ldc + col;
      if constexpr (EPI == E_ATOM) {
        atomicAdd(C + off, v);
      } else if constexpr (EPI == E_TANH) {
        float a = fminf(fmaxf(v * scale, -15.f), 15.f);
        float e = __expf(2.f * a);
        C[off] = (e - 1.f) / (e + 1.f);
      } else {
        if constexpr (EPI == E_BCOL) v += bp[col];
        if constexpr (EPI == E_BROW) v += bp[row];
        if constexpr (EPI == E_RELU) v = fmaxf(v + bp[col], 0.f);
        C[off] = v;
      }
    }
  }
}

extern "C" void kernel_launch(void* const* d_in, const int* in_sizes, int n_in,
                              void* d_out, int out_size, void* d_ws, size_t ws_size,
                              hipStream_t stream) {
  const float* x   = (const float*)d_in[0];
  const float* e1W = (const float*)d_in[1];
  const float* e1b = (const float*)d_in[2];
  const float* wqW = (const float*)d_in[3];
  const float* wqb = (const float*)d_in[4];
  // d_in[5], d_in[6] = wk_W, wk_b : dead code in the reference, skipped
  const float* wvW = (const float*)d_in[7];
  const float* wvb = (const float*)d_in[8];
  const float* e2W = (const float*)d_in[9];
  const float* e2b = (const float*)d_in[10];

  const size_t MB = 1 << 20;
  const long long S_x = (long long)NN * DD;        // 262144
  const long long S_e = (long long)NN * EE;        // 262144
  const long long S_info = (long long)NN * NN;     // 4194304
  const long long S_hc = (long long)NN * HH * EE;  // 1048576
  const long long S_w = (long long)EE * DD;        // 16384
  const float rs = 0.08838834764831845f;           // 1/sqrt(128)
  const ZMap Z0{1, 1, 0};

  // ws-adaptive: per-b ~18.3 MB (all f32), attn chunk G*16 MB.
  struct Cfg { int bch, g; };
  const Cfg cfgs[] = {{8,4},{8,2},{8,1},{4,2},{4,1},{2,1},{1,1}};
  int BCH = 1, G = 1;
  for (const Cfg& c : cfgs) {
    size_t per_b = (size_t)(S_w * 5 + S_x + S_e * 13 + S_hc) * 4;  // G1T+T2T+xT+emb+q+vT+WT+hcat
    size_t need = (size_t)c.bch * per_b + (size_t)c.g * S_info * 4 + 2 * MB;
    if (need <= ws_size) { BCH = c.bch; G = c.g; break; }
  }
  const int NBH = 4 * BCH;

  char* p = (char*)d_ws;
  auto carve = [&](size_t bytes) {
    char* r = p; p += (bytes + 255) & ~(size_t)255; return r;
  };
  // zero-span buffers first (atomic destinations): G1T, T2T, hcat
  float* G1T  = (float*)carve((size_t)BCH * S_w * 4);
  float* T2T  = (float*)carve((size_t)NBH * S_w * 4);
  float* hcat = (float*)carve((size_t)BCH * S_hc * 4);
  size_t zero_span = (size_t)(p - (char*)G1T);
  float* xT   = (float*)carve((size_t)BCH * S_x * 4);
  float* emb  = (float*)carve((size_t)BCH * S_e * 4);
  float* q    = (float*)carve((size_t)NBH * S_e * 4);
  float* vT   = (float*)carve((size_t)NBH * S_e * 4);
  float* WT   = (float*)carve((size_t)NBH * S_e * 4);
  float* attn = (float*)carve((size_t)G * S_info * 4);

  for (int bc = 0; bc < BB / BCH; ++bc) {
    const float* xc = x + (long long)bc * BCH * S_x;
    hipMemsetAsync(G1T, 0, zero_span, stream);
    transp_x<<<dim3(DD / 32, NN / 32, BCH), dim3(256), 0, stream>>>(xc, xT);

    // S1: G1T[b] = e1W @ xT[b]^T (= e1W x)      M=128,N'=128,K=2048, splitK=16
    gemm32<E_ATOM><<<dim3(1, 1, BCH * 16), 256, 0, stream>>>(
        e1W, Z0, xT, ZMap{16, BCH, S_x}, G1T, ZMap{16, BCH, S_w}, Z0,
        nullptr, Z0, 2048, 16, 2048, 2048, 128, 0.f);
    // S2: emb[b] = x[b] @ G1T[b]^T + e1b(col)   M=2048,N'=128,K=128
    gemm32<E_BCOL><<<dim3(1, 16, BCH), 256, 0, stream>>>(
        xc, ZMap{1, BCH, S_x}, G1T, ZMap{1, BCH, S_w}, emb, ZMap{1, BCH, S_e}, Z0,
        e1b, Z0, 128, 1, 128, 128, 128, 0.f);
    // S3a: q[bh] = emb[b] @ wq[h]^T + bq(col)   M=2048,N'=128,K=128
    gemm32<E_BCOL><<<dim3(1, 16, NBH), 256, 0, stream>>>(
        emb, ZMap{4, BCH, S_e}, wqW, ZMap{1, 4, S_w}, q, ZMap{1, NBH, S_e}, Z0,
        wqb, ZMap{1, 4, EE}, 128, 1, 128, 128, 128, 0.f);
    // S3b: vT[bh] = wv[h] @ emb[b]^T + bv(row)  M=128,N'=2048,K=128
    gemm32<E_BROW><<<dim3(16, 1, NBH), 256, 0, stream>>>(
        wvW, ZMap{1, 4, S_w}, emb, ZMap{4, BCH, S_e}, vT, ZMap{1, NBH, S_e}, Z0,
        wvb, ZMap{1, 4, EE}, 128, 1, 128, 128, 2048, 0.f);
    // S4a: T2T[bh] = vT[bh] @ xT[b]^T (= (x^T v)^T)  M=128,N'=128,K=2048, splitK=16
    gemm32<E_ATOM><<<dim3(1, 1, NBH * 16), 256, 0, stream>>>(
        vT, ZMap{16, NBH, S_e}, xT, ZMap{64, BCH, S_x}, T2T, ZMap{16, NBH, S_w}, Z0,
        nullptr, Z0, 2048, 16, 2048, 2048, 128, 0.f);
    // S4b: WT[bh] = x[b] @ T2T[bh]^T (= info v)      M=2048,N'=128,K=128
    gemm32<E_STORE><<<dim3(1, 16, NBH), 256, 0, stream>>>(
        xc, ZMap{4, BCH, S_x}, T2T, ZMap{1, NBH, S_w}, WT, ZMap{1, NBH, S_e}, Z0,
        nullptr, Z0, 128, 1, 128, 128, 128, 0.f);
    // S5/S6 per attn chunk of G (b,h) slices
    for (int c = 0; c < NBH / G; ++c) {
      long long o = (long long)c * G;
      // S5: attn[l] = tanh(q[o+l] @ WT[o+l]^T / sqrt(E))  M=N'=2048, K=128
      gemm32<E_TANH><<<dim3(16, 16, G), 256, 0, stream>>>(
          q + o * S_e, ZMap{1, 32, S_e}, WT + o * S_e, ZMap{1, 32, S_e},
          attn, ZMap{1, 32, S_info}, Z0, nullptr, Z0,
          128, 1, 128, 128, 2048, rs);
      // S6: hcat[b, :, h*128:] += attn[l] @ v[o+l]   M=2048,N'=128,K=2048, splitK=4
      //     z = l*4+kc: slice l via div4; b via div16; h-col via zc2 {4,4,128}
      gemm32<E_ATOM><<<dim3(1, 16, G * 4), 256, 0, stream>>>(
          attn, ZMap{4, 32, S_info}, vT + o * S_e, ZMap{4, 32, S_e},
          hcat + (o >> 2) * S_hc + (o & 3) * 128, ZMap{16, BCH, S_hc},
          ZMap{4, 4, 128}, nullptr, Z0, 2048, 4, 2048, 2048, 512, 0.f);
    }
    // S7: out[b] = relu(hcat[b] @ e2W^T + b2)   M=2048,N'=128,K=512
    gemm32<E_RELU><<<dim3(1, 16, BCH), 256, 0, stream>>>(
        hcat, ZMap{1, BCH, S_hc}, e2W, Z0,
        (float*)d_out + (long long)bc * BCH * S_e, ZMap{1, BCH, S_e}, Z0,
        e2b, Z0, 512, 1, 512, 512, 128, 0.f);
  }
}